// Round 7
// baseline (486.649 us; speedup 1.0000x reference)
//
#include <hip/hip_runtime.h>
#include <math.h>

#define TPB 256
static constexpr int N0  = 64;   // nodes per graph
static constexpr int H   = 128;  // hidden
static constexpr int XLD = 132;  // LDS row stride for feature tiles (16B aligned, bank-skewed)

#define SCHED_FENCE() __builtin_amdgcn_sched_barrier(0)

// LDS: no dedicated wtile — W k-tiles alias dead space in Xs/Zs per stage.
// Total 54272 B -> 3 blocks/CU (162816 <= 163840), vs 62464 B -> 2 blocks/CU.
struct alignas(16) Shm {
  unsigned long long adjM[N0];  // 512 B   adjacency bitmask rows (no self loops)
  float Xs[N0 * XLD];           // 33792 B ping buffer
  float Zs[32 * XLD];           // 16896 B pong buffer (z1 as [64][36]; MLP partials)
  float rbuf[2 * H];            // readout accumulator [max | mean]
  float uu[N0], vv[N0], sv[N0], tv[N0], dinv[N0];
  float h1[H];
  int   sel[N0];
};

template<int W>
__device__ __forceinline__ float redsum(float v) {
  #pragma unroll
  for (int m = W >> 1; m; m >>= 1) v += __shfl_xor(v, m, 64);
  return v;
}
template<int W>
__device__ __forceinline__ int redsum_i(int v) {
  #pragma unroll
  for (int m = W >> 1; m; m >>= 1) v += __shfl_xor(v, m, 64);
  return v;
}

// z[i][k] = dinv[i] * sum_{j in nbr(i) U {i}} dinv[j] * x[j][k]   (adj entries are {0,1})
// Skipping exact zeros in increasing-j order is bitwise-identical to the dense sum.
template<int NN, int NCH, int KCH>
__device__ __forceinline__ void norm_agg(const Shm& sh, const float* x, int xld,
                                         float* z, int zld, int tid) {
  #pragma unroll 1
  for (int it = tid; it < NN * NCH; it += TPB) {
    int i = it & (NN - 1);
    int g = it / NN;
    unsigned long long m = sh.adjM[i] | (1ull << i);  // A + I (diag of A is 0)
    float acc[KCH];
    #pragma unroll
    for (int c = 0; c < KCH; ++c) acc[c] = 0.f;
    #pragma unroll 1
    while (m) {
      int j = __builtin_ctzll(m); m &= m - 1;
      float a = sh.dinv[j];
      const float* xp = x + j * xld + g * KCH;
      #pragma unroll
      for (int c = 0; c < KCH; c += 4) {
        float4 xv = *(const float4*)(xp + c);
        acc[c]     += a * xv.x; acc[c + 1] += a * xv.y;
        acc[c + 2] += a * xv.z; acc[c + 3] += a * xv.w;
      }
    }
    float di = sh.dinv[i];
    #pragma unroll
    for (int c = 0; c < KCH; c += 4) {
      float4 r = make_float4(acc[c] * di, acc[c + 1] * di, acc[c + 2] * di, acc[c + 3] * di);
      *(float4*)(z + i * zld + g * KCH + c) = r;
    }
  }
}

// out[i][f] = relu(sum_k z[i][k]*W[k][f] + b[f]).
// W k-tile (KT rows) staged in LDS at caller-provided dead space `wt`.
template<int R, int K, int KREAL, int KT>
__device__ __forceinline__ void gemm_bias_relu(const float* z, int zld, float* wt,
    const float* __restrict__ Wg, const float* __restrict__ bg,
    float* out, int old_, int tid) {
  constexpr int NR = R / 4;
  const int f  = tid & 63;
  const int r0 = (tid >> 6) * NR;
  float acc0[NR], acc1[NR];
  #pragma unroll
  for (int r = 0; r < NR; ++r) { acc0[r] = 0.f; acc1[r] = 0.f; }
  #pragma unroll 1
  for (int kt = 0; kt < K; kt += KT) {
    __syncthreads();  // previous tile fully consumed
    constexpr int QN = (KT * H) / (TPB * 4);
    #pragma unroll
    for (int q = 0; q < QN; ++q) {
      int e = q * (TPB * 4) + tid * 4;
      int row = e >> 7, col = e & (H - 1);
      int rg = kt + row;
      float4 v = make_float4(0.f, 0.f, 0.f, 0.f);
      if (rg < KREAL) v = *(const float4*)(Wg + rg * H + col);
      *(float4*)(&wt[row * H + col]) = v;
    }
    __syncthreads();
    const int kn = (K - kt < KT) ? (K - kt) : KT;
    float w0[KT], w1[KT];
    #pragma unroll
    for (int k = 0; k < KT; ++k) {
      w0[k] = wt[k * H + f];
      w1[k] = wt[k * H + f + 64];
    }
    #pragma unroll
    for (int r = 0; r < NR; ++r) {
      const float* zr = z + (r0 + r) * zld + kt;
      #pragma unroll
      for (int k = 0; k < KT; k += 4) {
        if (k < kn) {
          float4 zv = *(const float4*)(zr + k);
          acc0[r] += zv.x * w0[k] + zv.y * w0[k + 1] + zv.z * w0[k + 2] + zv.w * w0[k + 3];
          acc1[r] += zv.x * w1[k] + zv.y * w1[k + 1] + zv.z * w1[k + 2] + zv.w * w1[k + 3];
        }
      }
    }
  }
  const float b0 = bg[f], b1 = bg[f + 64];
  #pragma unroll
  for (int r = 0; r < NR; ++r) {
    out[(r0 + r) * old_ + f]      = fmaxf(acc0[r] + b0, 0.f);
    out[(r0 + r) * old_ + f + 64] = fmaxf(acc1[r] + b1, 0.f);
  }
}

// SAGPool(NN->KK) + bitmask adjacency filter + next dinv + readout accumulate.
template<int NN, int KK, int UVP, int RKP, bool DODINV>
__device__ __forceinline__ void sag_pool_readout(Shm& sh,
    const float* x, float* xn,
    const float* __restrict__ wl, const float* __restrict__ blp,
    const float* __restrict__ wr, int tid) {
  { // u[j]=x[j].wl, v[j]=x[j].wr  (2*NN*UVP == TPB)
    int dot = tid / UVP, p = tid % UVP;
    int j = dot >> 1;
    const float* wp = (dot & 1) ? wr : wl;
    constexpr int CH = H / UVP;
    const float* xr = x + j * XLD + p * CH;
    const float* wq = wp + p * CH;
    float a = 0.f;
    #pragma unroll
    for (int k = 0; k < CH; k += 4) {
      float4 xv = *(const float4*)(xr + k);
      float4 wv = *(const float4*)(wq + k);
      a += xv.x * wv.x + xv.y * wv.y + xv.z * wv.z + xv.w * wv.w;
    }
    a = redsum<UVP>(a);
    if (p == 0) { if (dot & 1) sh.vv[j] = a; else sh.uu[j] = a; }
  }
  __syncthreads();
  SCHED_FENCE();
  // s[i] = sum_{j in nbr(i)} u[j] + bl + v[i]   (adj binary; in-order zero-skip)
  if (tid < NN) {
    unsigned long long m = sh.adjM[tid];
    float a = blp[0] + sh.vv[tid];
    #pragma unroll 1
    while (m) { int j = __builtin_ctzll(m); m &= m - 1; a += sh.uu[j]; }
    sh.sv[tid] = a;
  }
  __syncthreads();
  { // exact stable top-k via parallel rank counting (NN*RKP == TPB)
    int i = tid / RKP, p = tid % RKP;
    constexpr int CHr = NN / RKP;
    float si = sh.sv[i];
    int cnt = 0;
    #pragma unroll
    for (int c = 0; c < CHr; ++c) {
      int j = p * CHr + c;
      float sj = sh.sv[j];
      cnt += (sj > si || (sj == si && j < i)) ? 1 : 0;
    }
    cnt = redsum_i<RKP>(cnt);
    if (p == 0 && cnt < KK) { sh.sel[cnt] = i; sh.tv[cnt] = tanhf(si); }
  }
  __syncthreads();
  SCHED_FENCE();
  // phase A: gather x_next = x[sel]*tanh(s[sel]); snapshot old adj rows in regs
  unsigned long long oldrow = 0ull;
  if (tid < KK) oldrow = sh.adjM[sh.sel[tid]];
  constexpr int HV = H / 4;
  #pragma unroll 1
  for (int e = tid; e < KK * HV; e += TPB) {
    int r = e / HV, c = (e % HV) * 4;
    float4 v = *(const float4*)(x + sh.sel[r] * XLD + c);
    float t = sh.tv[r];
    *(float4*)(xn + r * XLD + c) = make_float4(v.x * t, v.y * t, v.z * t, v.w * t);
  }
  __syncthreads();
  // phase B: filtered bitmask adjacency + next dinv; readout accumulate
  if (tid < KK) {
    unsigned long long nm = 0ull;
    #pragma unroll 1
    for (int c = 0; c < KK; ++c)
      nm |= ((oldrow >> sh.sel[c]) & 1ull) << c;
    sh.adjM[tid] = nm;
    if (DODINV) sh.dinv[tid] = rsqrtf(1.f + (float)__popcll(nm));
  }
  if (tid < H) {
    float m = -INFINITY, s = 0.f;
    #pragma unroll
    for (int r = 0; r < KK; ++r) {
      float v = xn[r * XLD + tid];
      m = fmaxf(m, v); s += v;
    }
    sh.rbuf[tid]     += m;
    sh.rbuf[H + tid] += s * (1.f / KK);
  }
  __syncthreads();
  SCHED_FENCE();
}

__global__ __launch_bounds__(TPB, 2) void sagpool_fused(
    const int* __restrict__ aa, const float* __restrict__ pos,
    const float* __restrict__ cdr, const float* __restrict__ adjG,
    const float* __restrict__ emb,
    const float* __restrict__ W1, const float* __restrict__ b1,
    const float* __restrict__ p1wl, const float* __restrict__ p1bl, const float* __restrict__ p1wr,
    const float* __restrict__ W2, const float* __restrict__ b2,
    const float* __restrict__ p2wl, const float* __restrict__ p2bl, const float* __restrict__ p2wr,
    const float* __restrict__ W3, const float* __restrict__ b3,
    const float* __restrict__ p3wl, const float* __restrict__ p3bl, const float* __restrict__ p3wr,
    const float* __restrict__ mW1, const float* __restrict__ mb1,
    const float* __restrict__ mW2, const float* __restrict__ mb2,
    const float* __restrict__ mW3, const float* __restrict__ mb3,
    float* __restrict__ out)
{
  __shared__ Shm sh;
  const int b   = blockIdx.x;
  const int tid = threadIdx.x;

  sh.rbuf[tid] = 0.f;  // TPB == 2*H

  // adjacency [64][64] -> 64-bit row masks + fused degree/dinv
  {
    const float* rp = adjG + (size_t)b * (N0 * N0) + (tid >> 2) * N0 + (tid & 3) * 16;
    unsigned long long mpart = 0ull;
    #pragma unroll
    for (int q = 0; q < 16; q += 4) {
      float4 v = *(const float4*)(rp + q);
      unsigned int bits = (v.x != 0.f ? 1u : 0u) | (v.y != 0.f ? 2u : 0u)
                        | (v.z != 0.f ? 4u : 0u) | (v.w != 0.f ? 8u : 0u);
      mpart |= (unsigned long long)bits << q;
    }
    mpart <<= ((tid & 3) * 16);
    mpart |= __shfl_xor(mpart, 1, 64);
    mpart |= __shfl_xor(mpart, 2, 64);
    if ((tid & 3) == 0) {
      int r = tid >> 2;
      sh.adjM[r] = mpart;
      sh.dinv[r] = rsqrtf(1.f + (float)__popcll(mpart));
    }
  }
  SCHED_FENCE();
  // build x = [emb[aa] | pos | is_cdr3 | 0 0] into Xs cols 0..35
  #pragma unroll 1
  for (int e = tid; e < N0 * 36; e += TPB) {
    int j = e / 36, k = e - j * 36;
    int node = b * N0 + j;
    float v;
    if (k < 32)       v = emb[aa[node] * 32 + k];
    else if (k == 32) v = pos[node];
    else if (k == 33) v = cdr[node];
    else              v = 0.f;
    sh.Xs[j * XLD + k] = v;
  }
  __syncthreads();
  SCHED_FENCE();

  // ---- stage 1: GCN(34->128) on 64 nodes, pool 64->32 ----
  // z1 [64][36] occupies Zs[0..2304); W k-tile (8x128=1024 floats) at Zs+2304.
  norm_agg<64, 3, 12>(sh, sh.Xs, XLD, sh.Zs, 36, tid);
  __syncthreads();
  SCHED_FENCE();
  gemm_bias_relu<64, 36, 34, 8>(sh.Zs, 36, sh.Zs + 64 * 36, W1, b1, sh.Xs, XLD, tid);
  __syncthreads();
  SCHED_FENCE();
  sag_pool_readout<64, 32, 2, 4, true>(sh, sh.Xs, sh.Zs, p1wl, p1bl, p1wr, tid);

  // ---- stage 2: GCN(128->128) on 32 nodes, pool 32->16 ----
  // z2 in Xs rows 0..31; W k-tile (16x128=2048 floats) at Xs rows 32.. (offset 4224).
  norm_agg<32, 16, 8>(sh, sh.Zs, XLD, sh.Xs, XLD, tid);
  __syncthreads();
  SCHED_FENCE();
  gemm_bias_relu<32, 128, 128, 16>(sh.Xs, XLD, sh.Xs + 32 * XLD, W2, b2, sh.Zs, XLD, tid);
  __syncthreads();
  SCHED_FENCE();
  sag_pool_readout<32, 16, 4, 8, true>(sh, sh.Zs, sh.Xs, p2wl, p2bl, p2wr, tid);

  // ---- stage 3: GCN(128->128) on 16 nodes, pool 16->8 ----
  // z3 in Zs rows 0..15; output Xs rows 0..15; W k-tile again at Xs+4224 (rows 32..).
  norm_agg<16, 16, 8>(sh, sh.Xs, XLD, sh.Zs, XLD, tid);
  __syncthreads();
  SCHED_FENCE();
  gemm_bias_relu<16, 128, 128, 16>(sh.Zs, XLD, sh.Xs + 32 * XLD, W3, b3, sh.Xs, XLD, tid);
  __syncthreads();
  SCHED_FENCE();
  sag_pool_readout<16, 8, 8, 16, false>(sh, sh.Xs, sh.Zs, p3wl, p3bl, p3wr, tid);

  // ---- MLP head on rbuf[256] ----
  { // h1 partials: 128 f x 2 k-halves -> Zs[0..255]
    int f = tid & (H - 1), p = tid >> 7;
    const int base = p * 128;
    float a = 0.f;
    #pragma unroll 2
    for (int k = 0; k < 128; ++k) a += sh.rbuf[base + k] * mW1[(base + k) * H + f];
    sh.Zs[p * H + f] = a;
  }
  __syncthreads();
  SCHED_FENCE();
  if (tid < H) {
    float a = mb1[tid] + sh.Zs[tid] + sh.Zs[H + tid];
    sh.h1[tid] = fmaxf(a, 0.f);
  }
  __syncthreads();
  SCHED_FENCE();
  { // h2 partials: 64 o x 4 k-parts -> Zs[0..255]
    int o = tid & 63, p = tid >> 6;
    const int base = p * 32;
    float a = 0.f;
    #pragma unroll 2
    for (int k = 0; k < 32; ++k) a += sh.h1[base + k] * mW2[(base + k) * 64 + o];
    sh.Zs[p * 64 + o] = a;
  }
  __syncthreads();
  SCHED_FENCE();
  if (tid < 64) {
    float a = sh.Zs[tid] + sh.Zs[64 + tid] + sh.Zs[128 + tid] + sh.Zs[192 + tid];
    a = fmaxf(a + mb2[tid], 0.f);
    float v = a * mW3[tid];
    v = redsum<64>(v);
    if (tid == 0) out[b] = v + mb3[0];
  }
}

extern "C" void kernel_launch(void* const* d_in, const int* in_sizes, int n_in,
                              void* d_out, int out_size, void* d_ws, size_t ws_size,
                              hipStream_t stream) {
  (void)n_in; (void)d_ws; (void)ws_size; (void)out_size;
  const int*   aa   = (const int*)  d_in[0];
  const float* pos  = (const float*)d_in[1];
  const float* cdr  = (const float*)d_in[2];
  const float* adj  = (const float*)d_in[3];
  const float* emb  = (const float*)d_in[4];
  const float* W1   = (const float*)d_in[5];
  const float* b1   = (const float*)d_in[6];
  const float* p1wl = (const float*)d_in[7];
  const float* p1bl = (const float*)d_in[8];
  const float* p1wr = (const float*)d_in[9];
  const float* W2   = (const float*)d_in[10];
  const float* b2   = (const float*)d_in[11];
  const float* p2wl = (const float*)d_in[12];
  const float* p2bl = (const float*)d_in[13];
  const float* p2wr = (const float*)d_in[14];
  const float* W3   = (const float*)d_in[15];
  const float* b3   = (const float*)d_in[16];
  const float* p3wl = (const float*)d_in[17];
  const float* p3bl = (const float*)d_in[18];
  const float* p3wr = (const float*)d_in[19];
  const float* mW1  = (const float*)d_in[20];
  const float* mb1  = (const float*)d_in[21];
  const float* mW2  = (const float*)d_in[22];
  const float* mb2  = (const float*)d_in[23];
  const float* mW3  = (const float*)d_in[24];
  const float* mb3  = (const float*)d_in[25];
  float* out = (float*)d_out;

  const int B = in_sizes[0] / N0;  // 4096
  hipLaunchKernelGGL(sagpool_fused, dim3(B), dim3(TPB), 0, stream,
                     aa, pos, cdr, adj, emb,
                     W1, b1, p1wl, p1bl, p1wr,
                     W2, b2, p2wl, p2bl, p2wr,
                     W3, b3, p3wl, p3bl, p3wr,
                     mW1, mb1, mW2, mb2, mW3, mb3, out);
}

// Round 8
// 444.588 us; speedup vs baseline: 1.0946x; 1.0946x over previous
//
#include <hip/hip_runtime.h>
#include <math.h>

#define TPB 256
static constexpr int N0  = 64;   // nodes per graph
static constexpr int H   = 128;  // hidden
static constexpr int XLD = 132;  // LDS row stride for feature tiles (16B aligned, bank-skewed)

#define SCHED_FENCE() __builtin_amdgcn_sched_barrier(0)

typedef const __attribute__((address_space(1))) unsigned int glb_u32;
typedef __attribute__((address_space(3))) unsigned int lds_u32;

// LDS: W k-tile double-buffers alias dead rows of Xs per stage. 54272 B total.
struct alignas(16) Shm {
  unsigned long long adjM[N0];  // 512 B   adjacency bitmask rows (no self loops)
  float Xs[N0 * XLD];           // 33792 B ping buffer (+ W dbuf in dead rows)
  float Zs[32 * XLD];           // 16896 B pong buffer (z1 as [64][36]; MLP partials)
  float rbuf[2 * H];            // readout accumulator [max | mean]
  float uu[N0], vv[N0], sv[N0], tv[N0], dinv[N0];
  float h1[H];
  int   sel[N0];
};

template<int W>
__device__ __forceinline__ float redsum(float v) {
  #pragma unroll
  for (int m = W >> 1; m; m >>= 1) v += __shfl_xor(v, m, 64);
  return v;
}
template<int W>
__device__ __forceinline__ int redsum_i(int v) {
  #pragma unroll
  for (int m = W >> 1; m; m >>= 1) v += __shfl_xor(v, m, 64);
  return v;
}

// z[i][k] = dinv[i] * sum_{j in nbr(i) U {i}} dinv[j] * x[j][k]   (adj entries are {0,1})
template<int NN, int NCH, int KCH>
__device__ __forceinline__ void norm_agg(const Shm& sh, const float* x, int xld,
                                         float* z, int zld, int tid) {
  #pragma unroll 1
  for (int it = tid; it < NN * NCH; it += TPB) {
    int i = it & (NN - 1);
    int g = it / NN;
    unsigned long long m = sh.adjM[i] | (1ull << i);  // A + I (diag of A is 0)
    float acc[KCH];
    #pragma unroll
    for (int c = 0; c < KCH; ++c) acc[c] = 0.f;
    #pragma unroll 1
    while (m) {
      int j = __builtin_ctzll(m); m &= m - 1;
      float a = sh.dinv[j];
      const float* xp = x + j * xld + g * KCH;
      #pragma unroll
      for (int c = 0; c < KCH; c += 4) {
        float4 xv = *(const float4*)(xp + c);
        acc[c]     += a * xv.x; acc[c + 1] += a * xv.y;
        acc[c + 2] += a * xv.z; acc[c + 3] += a * xv.w;
      }
    }
    float di = sh.dinv[i];
    #pragma unroll
    for (int c = 0; c < KCH; c += 4) {
      float4 r = make_float4(acc[c] * di, acc[c + 1] * di, acc[c + 2] * di, acc[c + 3] * di);
      *(float4*)(z + i * zld + g * KCH + c) = r;
    }
  }
}

// Async DMA one W tile (KT rows x 128 cols, contiguous in global) into LDS.
// LDS dest: wave-uniform base; HW adds lane*16B. Global src: per-lane address.
template<int KT>
__device__ __forceinline__ void stage_async(const float* gsrc, float* ldst, int wv, int ln) {
  constexpr int NI = (KT * H * 4) / 4096;   // issues of 4096B (256 thr * 16B)
  #pragma unroll
  for (int q = 0; q < NI; ++q) {
    __builtin_amdgcn_global_load_lds(
        (glb_u32*)(gsrc + q * 1024 + wv * 256 + ln * 4),
        (lds_u32*)(ldst + q * 1024 + wv * 256),
        16, 0, 0);
  }
}

// out[i][f] = relu(sum_k z[i][k]*W[k][f] + b[f]).
// Double-buffered async W staging: DMA tile t+1 while computing tile t;
// one vmcnt(0)+barrier per tile. Partial tail tile staged synchronously w/ zeros.
template<int R, int K, int KREAL, int KT>
__device__ __forceinline__ void gemm_dbuf(const float* z, int zld,
    float* wt0, float* wt1,
    const float* __restrict__ Wg, const float* __restrict__ bg,
    float* out, int old_, int tid) {
  constexpr int NR = R / 4;
  const int f  = tid & 63;
  const int r0 = (tid >> 6) * NR;
  const int wv = tid >> 6;
  const int ln = tid & 63;
  float acc0[NR], acc1[NR];
  #pragma unroll
  for (int r = 0; r < NR; ++r) { acc0[r] = 0.f; acc1[r] = 0.f; }
  // prologue: tile 0 (always fully in-bounds: KT <= KREAL)
  stage_async<KT>(Wg, wt0, wv, ln);
  asm volatile("s_waitcnt vmcnt(0)" ::: "memory");
  __syncthreads();
  #pragma unroll 1
  for (int kt = 0; kt < K; kt += KT) {
    const int t = kt / KT;
    const float* cur = (t & 1) ? wt1 : wt0;
    float* nxt = (t & 1) ? wt0 : wt1;
    if (kt + KT < K) {
      const int nk = kt + KT;
      if (nk + KT <= KREAL) {
        stage_async<KT>(Wg + nk * H, nxt, wv, ln);
      } else {
        // bounds-checked sync staging with zero pad (stage-1 tail only)
        constexpr int QN = (KT * H) / (TPB * 4);
        #pragma unroll
        for (int q = 0; q < QN; ++q) {
          int e = q * (TPB * 4) + tid * 4;
          int row = e >> 7, col = e & (H - 1);
          float4 v = make_float4(0.f, 0.f, 0.f, 0.f);
          if (nk + row < KREAL) v = *(const float4*)(Wg + (nk + row) * H + col);
          *(float4*)(nxt + e) = v;
        }
      }
    }
    const int kn = (K - kt < KT) ? (K - kt) : KT;
    float w0[KT], w1[KT];
    #pragma unroll
    for (int k = 0; k < KT; ++k) {
      w0[k] = cur[k * H + f];
      w1[k] = cur[k * H + f + 64];
    }
    #pragma unroll
    for (int r = 0; r < NR; ++r) {
      const float* zr = z + (r0 + r) * zld + kt;
      #pragma unroll
      for (int k = 0; k < KT; k += 4) {
        if (k < kn) {
          float4 zv = *(const float4*)(zr + k);
          acc0[r] += zv.x * w0[k] + zv.y * w0[k + 1] + zv.z * w0[k + 2] + zv.w * w0[k + 3];
          acc1[r] += zv.x * w1[k] + zv.y * w1[k + 1] + zv.z * w1[k + 2] + zv.w * w1[k + 3];
        }
      }
    }
    asm volatile("s_waitcnt vmcnt(0)" ::: "memory");
    __syncthreads();
  }
  const float b0 = bg[f], b1 = bg[f + 64];
  #pragma unroll
  for (int r = 0; r < NR; ++r) {
    out[(r0 + r) * old_ + f]      = fmaxf(acc0[r] + b0, 0.f);
    out[(r0 + r) * old_ + f + 64] = fmaxf(acc1[r] + b1, 0.f);
  }
}

// SAGPool(NN->KK) + bitmask adjacency filter + next dinv + readout accumulate.
template<int NN, int KK, int UVP, int RKP, bool DODINV>
__device__ __forceinline__ void sag_pool_readout(Shm& sh,
    const float* x, float* xn,
    const float* __restrict__ wl, const float* __restrict__ blp,
    const float* __restrict__ wr, int tid) {
  { // u[j]=x[j].wl, v[j]=x[j].wr  (2*NN*UVP == TPB)
    int dot = tid / UVP, p = tid % UVP;
    int j = dot >> 1;
    const float* wp = (dot & 1) ? wr : wl;
    constexpr int CH = H / UVP;
    const float* xr = x + j * XLD + p * CH;
    const float* wq = wp + p * CH;
    float a = 0.f;
    #pragma unroll
    for (int k = 0; k < CH; k += 4) {
      float4 xv = *(const float4*)(xr + k);
      float4 wv = *(const float4*)(wq + k);
      a += xv.x * wv.x + xv.y * wv.y + xv.z * wv.z + xv.w * wv.w;
    }
    a = redsum<UVP>(a);
    if (p == 0) { if (dot & 1) sh.vv[j] = a; else sh.uu[j] = a; }
  }
  __syncthreads();
  SCHED_FENCE();
  // s[i] = sum_{j in nbr(i)} u[j] + bl + v[i]   (adj binary; in-order zero-skip)
  if (tid < NN) {
    unsigned long long m = sh.adjM[tid];
    float a = blp[0] + sh.vv[tid];
    #pragma unroll 1
    while (m) { int j = __builtin_ctzll(m); m &= m - 1; a += sh.uu[j]; }
    sh.sv[tid] = a;
  }
  __syncthreads();
  { // exact stable top-k via parallel rank counting (NN*RKP == TPB)
    int i = tid / RKP, p = tid % RKP;
    constexpr int CHr = NN / RKP;
    float si = sh.sv[i];
    int cnt = 0;
    #pragma unroll
    for (int c = 0; c < CHr; ++c) {
      int j = p * CHr + c;
      float sj = sh.sv[j];
      cnt += (sj > si || (sj == si && j < i)) ? 1 : 0;
    }
    cnt = redsum_i<RKP>(cnt);
    if (p == 0 && cnt < KK) { sh.sel[cnt] = i; sh.tv[cnt] = tanhf(si); }
  }
  __syncthreads();
  SCHED_FENCE();
  // phase A: gather x_next = x[sel]*tanh(s[sel]); snapshot old adj rows in regs
  unsigned long long oldrow = 0ull;
  if (tid < KK) oldrow = sh.adjM[sh.sel[tid]];
  constexpr int HV = H / 4;
  #pragma unroll 1
  for (int e = tid; e < KK * HV; e += TPB) {
    int r = e / HV, c = (e % HV) * 4;
    float4 v = *(const float4*)(x + sh.sel[r] * XLD + c);
    float t = sh.tv[r];
    *(float4*)(xn + r * XLD + c) = make_float4(v.x * t, v.y * t, v.z * t, v.w * t);
  }
  __syncthreads();
  // phase B: filtered bitmask adjacency + next dinv; readout accumulate
  if (tid < KK) {
    unsigned long long nm = 0ull;
    #pragma unroll 1
    for (int c = 0; c < KK; ++c)
      nm |= ((oldrow >> sh.sel[c]) & 1ull) << c;
    sh.adjM[tid] = nm;
    if (DODINV) sh.dinv[tid] = rsqrtf(1.f + (float)__popcll(nm));
  }
  if (tid < H) {
    float m = -INFINITY, s = 0.f;
    #pragma unroll
    for (int r = 0; r < KK; ++r) {
      float v = xn[r * XLD + tid];
      m = fmaxf(m, v); s += v;
    }
    sh.rbuf[tid]     += m;
    sh.rbuf[H + tid] += s * (1.f / KK);
  }
  __syncthreads();
  SCHED_FENCE();
}

__global__ __launch_bounds__(TPB, 2) void sagpool_fused(
    const int* __restrict__ aa, const float* __restrict__ pos,
    const float* __restrict__ cdr, const float* __restrict__ adjG,
    const float* __restrict__ emb,
    const float* __restrict__ W1, const float* __restrict__ b1,
    const float* __restrict__ p1wl, const float* __restrict__ p1bl, const float* __restrict__ p1wr,
    const float* __restrict__ W2, const float* __restrict__ b2,
    const float* __restrict__ p2wl, const float* __restrict__ p2bl, const float* __restrict__ p2wr,
    const float* __restrict__ W3, const float* __restrict__ b3,
    const float* __restrict__ p3wl, const float* __restrict__ p3bl, const float* __restrict__ p3wr,
    const float* __restrict__ mW1, const float* __restrict__ mb1,
    const float* __restrict__ mW2, const float* __restrict__ mb2,
    const float* __restrict__ mW3, const float* __restrict__ mb3,
    float* __restrict__ out)
{
  __shared__ Shm sh;
  const int b   = blockIdx.x;
  const int tid = threadIdx.x;

  sh.rbuf[tid] = 0.f;  // TPB == 2*H

  // adjacency [64][64] -> 64-bit row masks + fused degree/dinv
  {
    const float* rp = adjG + (size_t)b * (N0 * N0) + (tid >> 2) * N0 + (tid & 3) * 16;
    unsigned long long mpart = 0ull;
    #pragma unroll
    for (int q = 0; q < 16; q += 4) {
      float4 v = *(const float4*)(rp + q);
      unsigned int bits = (v.x != 0.f ? 1u : 0u) | (v.y != 0.f ? 2u : 0u)
                        | (v.z != 0.f ? 4u : 0u) | (v.w != 0.f ? 8u : 0u);
      mpart |= (unsigned long long)bits << q;
    }
    mpart <<= ((tid & 3) * 16);
    mpart |= __shfl_xor(mpart, 1, 64);
    mpart |= __shfl_xor(mpart, 2, 64);
    if ((tid & 3) == 0) {
      int r = tid >> 2;
      sh.adjM[r] = mpart;
      sh.dinv[r] = rsqrtf(1.f + (float)__popcll(mpart));
    }
  }
  SCHED_FENCE();
  // build x = [emb[aa] | pos | is_cdr3 | 0 0] into Xs cols 0..35
  #pragma unroll 1
  for (int e = tid; e < N0 * 36; e += TPB) {
    int j = e / 36, k = e - j * 36;
    int node = b * N0 + j;
    float v;
    if (k < 32)       v = emb[aa[node] * 32 + k];
    else if (k == 32) v = pos[node];
    else if (k == 33) v = cdr[node];
    else              v = 0.f;
    sh.Xs[j * XLD + k] = v;
  }
  __syncthreads();
  SCHED_FENCE();

  // ---- stage 1: GCN(34->128) on 64 nodes, pool 64->32 ----
  // z1 [64][36] in Zs; W dbuf (2x1024 floats) aliases Xs rows 48..63 (X input dead).
  norm_agg<64, 3, 12>(sh, sh.Xs, XLD, sh.Zs, 36, tid);
  __syncthreads();
  SCHED_FENCE();
  gemm_dbuf<64, 36, 34, 8>(sh.Zs, 36, sh.Xs + 48 * XLD, sh.Xs + 48 * XLD + 1024,
                           W1, b1, sh.Xs, XLD, tid);
  __syncthreads();
  SCHED_FENCE();
  sag_pool_readout<64, 32, 2, 4, true>(sh, sh.Xs, sh.Zs, p1wl, p1bl, p1wr, tid);

  // ---- stage 2: GCN(128->128) on 32 nodes, pool 32->16 ----
  // z2 in Xs rows 0..31; W dbuf (2x2048 floats) at Xs rows 32..47 / 48..63.
  norm_agg<32, 16, 8>(sh, sh.Zs, XLD, sh.Xs, XLD, tid);
  __syncthreads();
  SCHED_FENCE();
  gemm_dbuf<32, 128, 128, 16>(sh.Xs, XLD, sh.Xs + 32 * XLD, sh.Xs + 48 * XLD,
                              W2, b2, sh.Zs, XLD, tid);
  __syncthreads();
  SCHED_FENCE();
  sag_pool_readout<32, 16, 4, 8, true>(sh, sh.Zs, sh.Xs, p2wl, p2bl, p2wr, tid);

  // ---- stage 3: GCN(128->128) on 16 nodes, pool 16->8 ----
  norm_agg<16, 16, 8>(sh, sh.Xs, XLD, sh.Zs, XLD, tid);
  __syncthreads();
  SCHED_FENCE();
  gemm_dbuf<16, 128, 128, 16>(sh.Zs, XLD, sh.Xs + 32 * XLD, sh.Xs + 48 * XLD,
                              W3, b3, sh.Xs, XLD, tid);
  __syncthreads();
  SCHED_FENCE();
  sag_pool_readout<16, 8, 8, 16, false>(sh, sh.Xs, sh.Zs, p3wl, p3bl, p3wr, tid);

  // ---- MLP head on rbuf[256] ----
  { // h1 partials: 128 f x 2 k-halves -> Zs[0..255]
    int f = tid & (H - 1), p = tid >> 7;
    const int base = p * 128;
    float a = 0.f;
    #pragma unroll 4
    for (int k = 0; k < 128; ++k) a += sh.rbuf[base + k] * mW1[(base + k) * H + f];
    sh.Zs[p * H + f] = a;
  }
  __syncthreads();
  SCHED_FENCE();
  if (tid < H) {
    float a = mb1[tid] + sh.Zs[tid] + sh.Zs[H + tid];
    sh.h1[tid] = fmaxf(a, 0.f);
  }
  __syncthreads();
  SCHED_FENCE();
  { // h2 partials: 64 o x 4 k-parts -> Zs[0..255]
    int o = tid & 63, p = tid >> 6;
    const int base = p * 32;
    float a = 0.f;
    #pragma unroll 4
    for (int k = 0; k < 32; ++k) a += sh.h1[base + k] * mW2[(base + k) * 64 + o];
    sh.Zs[p * 64 + o] = a;
  }
  __syncthreads();
  SCHED_FENCE();
  if (tid < 64) {
    float a = sh.Zs[tid] + sh.Zs[64 + tid] + sh.Zs[128 + tid] + sh.Zs[192 + tid];
    a = fmaxf(a + mb2[tid], 0.f);
    float v = a * mW3[tid];
    v = redsum<64>(v);
    if (tid == 0) out[b] = v + mb3[0];
  }
}

extern "C" void kernel_launch(void* const* d_in, const int* in_sizes, int n_in,
                              void* d_out, int out_size, void* d_ws, size_t ws_size,
                              hipStream_t stream) {
  (void)n_in; (void)d_ws; (void)ws_size; (void)out_size;
  const int*   aa   = (const int*)  d_in[0];
  const float* pos  = (const float*)d_in[1];
  const float* cdr  = (const float*)d_in[2];
  const float* adj  = (const float*)d_in[3];
  const float* emb  = (const float*)d_in[4];
  const float* W1   = (const float*)d_in[5];
  const float* b1   = (const float*)d_in[6];
  const float* p1wl = (const float*)d_in[7];
  const float* p1bl = (const float*)d_in[8];
  const float* p1wr = (const float*)d_in[9];
  const float* W2   = (const float*)d_in[10];
  const float* b2   = (const float*)d_in[11];
  const float* p2wl = (const float*)d_in[12];
  const float* p2bl = (const float*)d_in[13];
  const float* p2wr = (const float*)d_in[14];
  const float* W3   = (const float*)d_in[15];
  const float* b3   = (const float*)d_in[16];
  const float* p3wl = (const float*)d_in[17];
  const float* p3bl = (const float*)d_in[18];
  const float* p3wr = (const float*)d_in[19];
  const float* mW1  = (const float*)d_in[20];
  const float* mb1  = (const float*)d_in[21];
  const float* mW2  = (const float*)d_in[22];
  const float* mb2  = (const float*)d_in[23];
  const float* mW3  = (const float*)d_in[24];
  const float* mb3  = (const float*)d_in[25];
  float* out = (float*)d_out;

  const int B = in_sizes[0] / N0;  // 4096
  hipLaunchKernelGGL(sagpool_fused, dim3(B), dim3(TPB), 0, stream,
                     aa, pos, cdr, adj, emb,
                     W1, b1, p1wl, p1bl, p1wr,
                     W2, b2, p2wl, p2bl, p2wr,
                     W3, b3, p3wl, p3bl, p3wr,
                     mW1, mb1, mW2, mb2, mW3, mb3, out);
}

// Round 9
// 341.889 us; speedup vs baseline: 1.4234x; 1.3004x over previous
//
#include <hip/hip_runtime.h>
#include <math.h>

#define TPB 256
static constexpr int N0  = 64;   // nodes per graph
static constexpr int H   = 128;  // hidden
static constexpr int XLD = 132;  // LDS row stride for feature tiles (16B aligned, bank-skewed)

#define SCHED_FENCE() __builtin_amdgcn_sched_barrier(0)

typedef const __attribute__((address_space(1))) unsigned int glb_u32;
typedef __attribute__((address_space(3))) unsigned int lds_u32;

// LDS diet: rbuf -> registers, h1 -> Zs alias, vv -> folded into sv.
// Total 52480 B; target 3 blocks/CU (52480*3 = 157440 <= 163840 even with
// 2-4KB allocation granularity rounding to 53248).
struct alignas(16) Shm {
  unsigned long long adjM[N0];  // 512 B   adjacency bitmask rows (no self loops)
  float Xs[N0 * XLD];           // 33792 B ping buffer (+ W dbuf in dead rows)
  float Zs[32 * XLD];           // 16896 B pong buffer (z1; MLP scratch at end)
  float uu[N0];                 // u = x.wl
  float sv[N0];                 // v then score
  float tv[N0];                 // tanh(score) of selected
  float dinv[N0];
  int   sel[N0];
};

template<int W>
__device__ __forceinline__ float redsum(float v) {
  #pragma unroll
  for (int m = W >> 1; m; m >>= 1) v += __shfl_xor(v, m, 64);
  return v;
}
template<int W>
__device__ __forceinline__ int redsum_i(int v) {
  #pragma unroll
  for (int m = W >> 1; m; m >>= 1) v += __shfl_xor(v, m, 64);
  return v;
}

// z[i][k] = dinv[i] * sum_{j in nbr(i) U {i}} dinv[j] * x[j][k]   (adj entries are {0,1})
template<int NN, int NCH, int KCH>
__device__ __forceinline__ void norm_agg(const Shm& sh, const float* x, int xld,
                                         float* z, int zld, int tid) {
  #pragma unroll 1
  for (int it = tid; it < NN * NCH; it += TPB) {
    int i = it & (NN - 1);
    int g = it / NN;
    unsigned long long m = sh.adjM[i] | (1ull << i);  // A + I (diag of A is 0)
    float acc[KCH];
    #pragma unroll
    for (int c = 0; c < KCH; ++c) acc[c] = 0.f;
    #pragma unroll 1
    while (m) {
      int j = __builtin_ctzll(m); m &= m - 1;
      float a = sh.dinv[j];
      const float* xp = x + j * xld + g * KCH;
      #pragma unroll
      for (int c = 0; c < KCH; c += 4) {
        float4 xv = *(const float4*)(xp + c);
        acc[c]     += a * xv.x; acc[c + 1] += a * xv.y;
        acc[c + 2] += a * xv.z; acc[c + 3] += a * xv.w;
      }
    }
    float di = sh.dinv[i];
    #pragma unroll
    for (int c = 0; c < KCH; c += 4) {
      float4 r = make_float4(acc[c] * di, acc[c + 1] * di, acc[c + 2] * di, acc[c + 3] * di);
      *(float4*)(z + i * zld + g * KCH + c) = r;
    }
  }
}

// Async DMA one W tile (KT rows x 128 cols, contiguous in global) into LDS.
template<int KT>
__device__ __forceinline__ void stage_async(const float* gsrc, float* ldst, int wv, int ln) {
  constexpr int NI = (KT * H * 4) / 4096;   // issues of 4096B (256 thr * 16B)
  #pragma unroll
  for (int q = 0; q < NI; ++q) {
    __builtin_amdgcn_global_load_lds(
        (glb_u32*)(gsrc + q * 1024 + wv * 256 + ln * 4),
        (lds_u32*)(ldst + q * 1024 + wv * 256),
        16, 0, 0);
  }
}

// out[i][f] = relu(sum_k z[i][k]*W[k][f] + b[f]).
// Double-buffered async W staging; one vmcnt(0)+barrier per tile.
template<int R, int K, int KREAL, int KT>
__device__ __forceinline__ void gemm_dbuf(const float* z, int zld,
    float* wt0, float* wt1,
    const float* __restrict__ Wg, const float* __restrict__ bg,
    float* out, int old_, int tid) {
  constexpr int NR = R / 4;
  const int f  = tid & 63;
  const int r0 = (tid >> 6) * NR;
  const int wv = tid >> 6;
  const int ln = tid & 63;
  float acc0[NR], acc1[NR];
  #pragma unroll
  for (int r = 0; r < NR; ++r) { acc0[r] = 0.f; acc1[r] = 0.f; }
  stage_async<KT>(Wg, wt0, wv, ln);
  asm volatile("s_waitcnt vmcnt(0)" ::: "memory");
  __syncthreads();
  #pragma unroll 1
  for (int kt = 0; kt < K; kt += KT) {
    const int t = kt / KT;
    const float* cur = (t & 1) ? wt1 : wt0;
    float* nxt = (t & 1) ? wt0 : wt1;
    if (kt + KT < K) {
      const int nk = kt + KT;
      if (nk + KT <= KREAL) {
        stage_async<KT>(Wg + nk * H, nxt, wv, ln);
      } else {
        constexpr int QN = (KT * H) / (TPB * 4);
        #pragma unroll
        for (int q = 0; q < QN; ++q) {
          int e = q * (TPB * 4) + tid * 4;
          int row = e >> 7, col = e & (H - 1);
          float4 v = make_float4(0.f, 0.f, 0.f, 0.f);
          if (nk + row < KREAL) v = *(const float4*)(Wg + (nk + row) * H + col);
          *(float4*)(nxt + e) = v;
        }
      }
    }
    const int kn = (K - kt < KT) ? (K - kt) : KT;
    float w0[KT], w1[KT];
    #pragma unroll
    for (int k = 0; k < KT; ++k) {
      w0[k] = cur[k * H + f];
      w1[k] = cur[k * H + f + 64];
    }
    #pragma unroll
    for (int r = 0; r < NR; ++r) {
      const float* zr = z + (r0 + r) * zld + kt;
      #pragma unroll
      for (int k = 0; k < KT; k += 4) {
        if (k < kn) {
          float4 zv = *(const float4*)(zr + k);
          acc0[r] += zv.x * w0[k] + zv.y * w0[k + 1] + zv.z * w0[k + 2] + zv.w * w0[k + 3];
          acc1[r] += zv.x * w1[k] + zv.y * w1[k + 1] + zv.z * w1[k + 2] + zv.w * w1[k + 3];
        }
      }
    }
    asm volatile("s_waitcnt vmcnt(0)" ::: "memory");
    __syncthreads();
  }
  const float b0 = bg[f], b1 = bg[f + 64];
  #pragma unroll
  for (int r = 0; r < NR; ++r) {
    out[(r0 + r) * old_ + f]      = fmaxf(acc0[r] + b0, 0.f);
    out[(r0 + r) * old_ + f + 64] = fmaxf(acc1[r] + b1, 0.f);
  }
}

// SAGPool(NN->KK) + bitmask adjacency filter + next dinv + register readout accum.
template<int NN, int KK, int UVP, int RKP, bool DODINV>
__device__ __forceinline__ void sag_pool_readout(Shm& sh,
    const float* x, float* xn,
    const float* __restrict__ wl, const float* __restrict__ blp,
    const float* __restrict__ wr, int tid, float& rm, float& rs) {
  { // u[j]=x[j].wl -> uu, v[j]=x[j].wr -> sv  (2*NN*UVP == TPB)
    int dot = tid / UVP, p = tid % UVP;
    int j = dot >> 1;
    const float* wp = (dot & 1) ? wr : wl;
    constexpr int CH = H / UVP;
    const float* xr = x + j * XLD + p * CH;
    const float* wq = wp + p * CH;
    float a = 0.f;
    #pragma unroll
    for (int k = 0; k < CH; k += 4) {
      float4 xv = *(const float4*)(xr + k);
      float4 wv = *(const float4*)(wq + k);
      a += xv.x * wv.x + xv.y * wv.y + xv.z * wv.z + xv.w * wv.w;
    }
    a = redsum<UVP>(a);
    if (p == 0) { if (dot & 1) sh.sv[j] = a; else sh.uu[j] = a; }
  }
  __syncthreads();
  SCHED_FENCE();
  // s[i] = sum_{j in nbr(i)} u[j] + bl + v[i]   (v already in sv[i]; RMW own slot)
  if (tid < NN) {
    unsigned long long m = sh.adjM[tid];
    float a = blp[0] + sh.sv[tid];
    #pragma unroll 1
    while (m) { int j = __builtin_ctzll(m); m &= m - 1; a += sh.uu[j]; }
    sh.sv[tid] = a;
  }
  __syncthreads();
  { // exact stable top-k via parallel rank counting (NN*RKP == TPB)
    int i = tid / RKP, p = tid % RKP;
    constexpr int CHr = NN / RKP;
    float si = sh.sv[i];
    int cnt = 0;
    #pragma unroll
    for (int c = 0; c < CHr; ++c) {
      int j = p * CHr + c;
      float sj = sh.sv[j];
      cnt += (sj > si || (sj == si && j < i)) ? 1 : 0;
    }
    cnt = redsum_i<RKP>(cnt);
    if (p == 0 && cnt < KK) { sh.sel[cnt] = i; sh.tv[cnt] = tanhf(si); }
  }
  __syncthreads();
  SCHED_FENCE();
  // phase A: gather x_next = x[sel]*tanh(s[sel]); snapshot old adj rows in regs
  unsigned long long oldrow = 0ull;
  if (tid < KK) oldrow = sh.adjM[sh.sel[tid]];
  constexpr int HV = H / 4;
  #pragma unroll 1
  for (int e = tid; e < KK * HV; e += TPB) {
    int r = e / HV, c = (e % HV) * 4;
    float4 v = *(const float4*)(x + sh.sel[r] * XLD + c);
    float t = sh.tv[r];
    *(float4*)(xn + r * XLD + c) = make_float4(v.x * t, v.y * t, v.z * t, v.w * t);
  }
  __syncthreads();
  // phase B: filtered bitmask adjacency + next dinv; readout accumulate (regs)
  if (tid < KK) {
    unsigned long long nm = 0ull;
    #pragma unroll 1
    for (int c = 0; c < KK; ++c)
      nm |= ((oldrow >> sh.sel[c]) & 1ull) << c;
    sh.adjM[tid] = nm;
    if (DODINV) sh.dinv[tid] = rsqrtf(1.f + (float)__popcll(nm));
  }
  if (tid < H) {
    float m = -INFINITY, s = 0.f;
    #pragma unroll
    for (int r = 0; r < KK; ++r) {
      float v = xn[r * XLD + tid];
      m = fmaxf(m, v); s += v;
    }
    rm += m;
    rs += s * (1.f / KK);
  }
  __syncthreads();
  SCHED_FENCE();
}

__global__ __launch_bounds__(TPB, 3) void sagpool_fused(
    const int* __restrict__ aa, const float* __restrict__ pos,
    const float* __restrict__ cdr, const float* __restrict__ adjG,
    const float* __restrict__ emb,
    const float* __restrict__ W1, const float* __restrict__ b1,
    const float* __restrict__ p1wl, const float* __restrict__ p1bl, const float* __restrict__ p1wr,
    const float* __restrict__ W2, const float* __restrict__ b2,
    const float* __restrict__ p2wl, const float* __restrict__ p2bl, const float* __restrict__ p2wr,
    const float* __restrict__ W3, const float* __restrict__ b3,
    const float* __restrict__ p3wl, const float* __restrict__ p3bl, const float* __restrict__ p3wr,
    const float* __restrict__ mW1, const float* __restrict__ mb1,
    const float* __restrict__ mW2, const float* __restrict__ mb2,
    const float* __restrict__ mW3, const float* __restrict__ mb3,
    float* __restrict__ out)
{
  __shared__ Shm sh;
  const int b   = blockIdx.x;
  const int tid = threadIdx.x;

  float rm = 0.f, rs = 0.f;   // readout accumulators (feature f = tid, tid < 128)

  // adjacency [64][64] -> 64-bit row masks + fused degree/dinv
  {
    const float* rp = adjG + (size_t)b * (N0 * N0) + (tid >> 2) * N0 + (tid & 3) * 16;
    unsigned long long mpart = 0ull;
    #pragma unroll
    for (int q = 0; q < 16; q += 4) {
      float4 v = *(const float4*)(rp + q);
      unsigned int bits = (v.x != 0.f ? 1u : 0u) | (v.y != 0.f ? 2u : 0u)
                        | (v.z != 0.f ? 4u : 0u) | (v.w != 0.f ? 8u : 0u);
      mpart |= (unsigned long long)bits << q;
    }
    mpart <<= ((tid & 3) * 16);
    mpart |= __shfl_xor(mpart, 1, 64);
    mpart |= __shfl_xor(mpart, 2, 64);
    if ((tid & 3) == 0) {
      int r = tid >> 2;
      sh.adjM[r] = mpart;
      sh.dinv[r] = rsqrtf(1.f + (float)__popcll(mpart));
    }
  }
  SCHED_FENCE();
  // build x = [emb[aa] | pos | is_cdr3 | 0 0] into Xs cols 0..35
  #pragma unroll 1
  for (int e = tid; e < N0 * 36; e += TPB) {
    int j = e / 36, k = e - j * 36;
    int node = b * N0 + j;
    float v;
    if (k < 32)       v = emb[aa[node] * 32 + k];
    else if (k == 32) v = pos[node];
    else if (k == 33) v = cdr[node];
    else              v = 0.f;
    sh.Xs[j * XLD + k] = v;
  }
  __syncthreads();
  SCHED_FENCE();

  // ---- stage 1: GCN(34->128) on 64 nodes, pool 64->32 ----
  norm_agg<64, 3, 12>(sh, sh.Xs, XLD, sh.Zs, 36, tid);
  __syncthreads();
  SCHED_FENCE();
  gemm_dbuf<64, 36, 34, 8>(sh.Zs, 36, sh.Xs + 48 * XLD, sh.Xs + 48 * XLD + 1024,
                           W1, b1, sh.Xs, XLD, tid);
  __syncthreads();
  SCHED_FENCE();
  sag_pool_readout<64, 32, 2, 4, true>(sh, sh.Xs, sh.Zs, p1wl, p1bl, p1wr, tid, rm, rs);

  // ---- stage 2: GCN(128->128) on 32 nodes, pool 32->16 ----
  norm_agg<32, 16, 8>(sh, sh.Zs, XLD, sh.Xs, XLD, tid);
  __syncthreads();
  SCHED_FENCE();
  gemm_dbuf<32, 128, 128, 16>(sh.Xs, XLD, sh.Xs + 32 * XLD, sh.Xs + 48 * XLD,
                              W2, b2, sh.Zs, XLD, tid);
  __syncthreads();
  SCHED_FENCE();
  sag_pool_readout<32, 16, 4, 8, true>(sh, sh.Zs, sh.Xs, p2wl, p2bl, p2wr, tid, rm, rs);

  // ---- stage 3: GCN(128->128) on 16 nodes, pool 16->8 ----
  norm_agg<16, 16, 8>(sh, sh.Xs, XLD, sh.Zs, XLD, tid);
  __syncthreads();
  SCHED_FENCE();
  gemm_dbuf<16, 128, 128, 16>(sh.Zs, XLD, sh.Xs + 32 * XLD, sh.Xs + 48 * XLD,
                              W3, b3, sh.Xs, XLD, tid);
  __syncthreads();
  SCHED_FENCE();
  sag_pool_readout<16, 8, 8, 16, false>(sh, sh.Xs, sh.Zs, p3wl, p3bl, p3wr, tid, rm, rs);

  // ---- MLP head ----
  // Zs is dead now. Layout: rbuf [0..256) | h1 [256..384) | h1p [384..640) | h2p [640..896)
  if (tid < H) { sh.Zs[tid] = rm; sh.Zs[H + tid] = rs; }
  __syncthreads();
  SCHED_FENCE();
  { // h1 partials: 128 f x 2 k-halves
    int f = tid & (H - 1), p = tid >> 7;
    const int base = p * 128;
    float a = 0.f;
    #pragma unroll 4
    for (int k = 0; k < 128; ++k) a += sh.Zs[base + k] * mW1[(base + k) * H + f];
    sh.Zs[384 + p * H + f] = a;
  }
  __syncthreads();
  SCHED_FENCE();
  if (tid < H) {
    float a = mb1[tid] + sh.Zs[384 + tid] + sh.Zs[384 + H + tid];
    sh.Zs[256 + tid] = fmaxf(a, 0.f);
  }
  __syncthreads();
  SCHED_FENCE();
  { // h2 partials: 64 o x 4 k-parts
    int o = tid & 63, p = tid >> 6;
    const int base = p * 32;
    float a = 0.f;
    #pragma unroll 4
    for (int k = 0; k < 32; ++k) a += sh.Zs[256 + base + k] * mW2[(base + k) * 64 + o];
    sh.Zs[640 + p * 64 + o] = a;
  }
  __syncthreads();
  SCHED_FENCE();
  if (tid < 64) {
    float a = sh.Zs[640 + tid] + sh.Zs[704 + tid] + sh.Zs[768 + tid] + sh.Zs[832 + tid];
    a = fmaxf(a + mb2[tid], 0.f);
    float v = a * mW3[tid];
    v = redsum<64>(v);
    if (tid == 0) out[b] = v + mb3[0];
  }
}

extern "C" void kernel_launch(void* const* d_in, const int* in_sizes, int n_in,
                              void* d_out, int out_size, void* d_ws, size_t ws_size,
                              hipStream_t stream) {
  (void)n_in; (void)d_ws; (void)ws_size; (void)out_size;
  const int*   aa   = (const int*)  d_in[0];
  const float* pos  = (const float*)d_in[1];
  const float* cdr  = (const float*)d_in[2];
  const float* adj  = (const float*)d_in[3];
  const float* emb  = (const float*)d_in[4];
  const float* W1   = (const float*)d_in[5];
  const float* b1   = (const float*)d_in[6];
  const float* p1wl = (const float*)d_in[7];
  const float* p1bl = (const float*)d_in[8];
  const float* p1wr = (const float*)d_in[9];
  const float* W2   = (const float*)d_in[10];
  const float* b2   = (const float*)d_in[11];
  const float* p2wl = (const float*)d_in[12];
  const float* p2bl = (const float*)d_in[13];
  const float* p2wr = (const float*)d_in[14];
  const float* W3   = (const float*)d_in[15];
  const float* b3   = (const float*)d_in[16];
  const float* p3wl = (const float*)d_in[17];
  const float* p3bl = (const float*)d_in[18];
  const float* p3wr = (const float*)d_in[19];
  const float* mW1  = (const float*)d_in[20];
  const float* mb1  = (const float*)d_in[21];
  const float* mW2  = (const float*)d_in[22];
  const float* mb2  = (const float*)d_in[23];
  const float* mW3  = (const float*)d_in[24];
  const float* mb3  = (const float*)d_in[25];
  float* out = (float*)d_out;

  const int B = in_sizes[0] / N0;  // 4096
  hipLaunchKernelGGL(sagpool_fused, dim3(B), dim3(TPB), 0, stream,
                     aa, pos, cdr, adj, emb,
                     W1, b1, p1wl, p1bl, p1wr,
                     W2, b2, p2wl, p2bl, p2wr,
                     W3, b3, p3wl, p3bl, p3wr,
                     mW1, mb1, mW2, mb2, mW3, mb3, out);
}